// Round 10
// baseline (249.482 us; speedup 1.0000x reference)
//
#include <hip/hip_runtime.h>
#include <hip/hip_fp16.h>
#include <math.h>

#define N_NODES 60000
#define N_EDGES 240000
#define F_INQ 10
#define G_DIM 512
#define NB_SCAN ((N_NODES + 255) / 256)   // 235
#define NB_EDGE ((N_EDGES + 255) / 256)   // 938

// ===========================================================================
// K_prep: fused degree histogram + graph-segment table + weight transpose.
//   blocks [0,NB_EDGE): degree histogram
//   blocks [NB_EDGE, NB_EDGE+NB_SCAN): gs table
//   block NB_EDGE+NB_SCAN: build per-output weight rows for the tf kernels:
//     Wc1[16][50]  = [be1-mat | We1_s0 | We1_s1 | We1_s2 | root1] per o
//     Wgt1[16][10] = Wg1 column per o
//     Wc2[32][80]  = [be2-mat | We2_s0 | We2_s1 | We2_s2 | root2] per o
//     Wgt2[32][16] = Wg2 column per o
//   Row-major per o so tf kernels read them with wave-UNIFORM indices
//   -> compiler emits s_load (SGPR operands, zero VGPR pressure).
// ===========================================================================
__global__ __launch_bounds__(256) void k_prep(
    const int* __restrict__ ei, int* __restrict__ rs,
    const int* __restrict__ seg, int* __restrict__ gs,
    const float* __restrict__ Wg1, const float* __restrict__ We1,
    const float* __restrict__ be1, const float* __restrict__ root1,
    const float* __restrict__ Wg2, const float* __restrict__ We2,
    const float* __restrict__ be2, const float* __restrict__ root2,
    float* __restrict__ Wblk)
{
    if (blockIdx.x < NB_EDGE) {
        int e = blockIdx.x * 256 + threadIdx.x;
        if (e < N_EDGES) atomicAdd(&rs[ei[e]], 1);
    } else if (blockIdx.x < NB_EDGE + NB_SCAN) {
        int i = (blockIdx.x - NB_EDGE) * 256 + threadIdx.x;
        if (i >= N_NODES) return;
        int s = seg[i];
        if (i == 0) { for (int g = 0; g <= s; ++g) gs[g] = 0; }
        else {
            int pr = seg[i - 1];
            for (int g = pr + 1; g <= s; ++g) gs[g] = i;
        }
        if (i == N_NODES - 1) { for (int g = s + 1; g <= G_DIM; ++g) gs[g] = N_NODES; }
    } else {
        // weight transpose: 800 + 160 + 2560 + 512 = 4032 entries
        for (int t = threadIdx.x; t < 4032; t += 256) {
            float v;
            if (t < 800) {                       // Wc1[o][i], o=t/50
                int o = t / 50, i = t - o * 50;
                if (i < 10)      v = be1[i * 16 + o];
                else if (i < 20) v = We1[(i - 10) * 16 + o];
                else if (i < 30) v = We1[160 + (i - 20) * 16 + o];
                else if (i < 40) v = We1[320 + (i - 30) * 16 + o];
                else             v = root1[(i - 40) * 16 + o];
            } else if (t < 960) {                // Wgt1[o][f]
                int j = t - 800; int o = j / 10, f = j - o * 10;
                v = Wg1[f * 16 + o];
            } else if (t < 3520) {               // Wc2[o][i]
                int j = t - 960; int o = j / 80, i = j - o * 80;
                if (i < 16)      v = be2[i * 32 + o];
                else if (i < 32) v = We2[(i - 16) * 32 + o];
                else if (i < 48) v = We2[512 + (i - 32) * 32 + o];
                else if (i < 64) v = We2[1024 + (i - 48) * 32 + o];
                else             v = root2[(i - 64) * 32 + o];
            } else {                             // Wgt2[o][f]
                int j = t - 3520; int o = j / 16, f = j - o * 16;
                v = Wg2[f * 32 + o];
            }
            Wblk[t] = v;
        }
    }
}

// ===========================================================================
// K_scan: per-block exclusive scan of rs + block totals; last block (ticket)
// exclusive-scans bsum in place. Global offset = rs[i] + bsum[i>>8].
// ===========================================================================
__global__ __launch_bounds__(256) void k_scan(
    int* __restrict__ rs, int* __restrict__ bsum, int* __restrict__ cnt)
{
    __shared__ int s[256];
    __shared__ int amLast;
    int i = blockIdx.x * 256 + threadIdx.x;
    int v = (i < N_NODES) ? rs[i] : 0;
    s[threadIdx.x] = v;
    __syncthreads();
    for (int off = 1; off < 256; off <<= 1) {
        int t = (threadIdx.x >= off) ? s[threadIdx.x - off] : 0;
        __syncthreads();
        s[threadIdx.x] += t;
        __syncthreads();
    }
    if (i < N_NODES) rs[i] = s[threadIdx.x] - v;  // block-local exclusive
    __syncthreads();
    if (threadIdx.x == 0) {
        bsum[blockIdx.x] = s[255];
        __threadfence();
        amLast = (atomicAdd(cnt, 1) == (int)gridDim.x - 1);
    }
    __syncthreads();
    if (!amLast) return;
    __threadfence();
    int b = (threadIdx.x < NB_SCAN) ? bsum[threadIdx.x] : 0;
    s[threadIdx.x] = b;
    __syncthreads();
    for (int off = 1; off < 256; off <<= 1) {
        int t = (threadIdx.x >= off) ? s[threadIdx.x - off] : 0;
        __syncthreads();
        s[threadIdx.x] += t;
        __syncthreads();
    }
    if (threadIdx.x < NB_SCAN) bsum[threadIdx.x] = s[threadIdx.x] - b;
}

__global__ __launch_bounds__(256) void k_fill(
    const int* __restrict__ ei, const float* __restrict__ a_vals,
    const float* __restrict__ efeat,
    int* __restrict__ rs, const int* __restrict__ bsum,
    int* __restrict__ ecol, float4* __restrict__ edata)
{
    int e = blockIdx.x * 256 + threadIdx.x;
    if (e >= N_EDGES) return;
    int row = ei[e];
    int slot = atomicAdd(&rs[row], 1) + bsum[row >> 8];
    ecol[slot] = ei[N_EDGES + e];
    edata[slot] = make_float4(a_vals[e], efeat[e * 3], efeat[e * 3 + 1], efeat[e * 3 + 2]);
}

// ---------------------------------------------------------------------------
// K_edge1: weight-free CSR reduction, layer 1. Lane = (node, f<10) PACKED.
// PQ1 row stride 52 (208 B, 16-B aligned for tf1's float4 reads).
// ---------------------------------------------------------------------------
__global__ __launch_bounds__(256) void k_edge1(
    const float* __restrict__ x,
    const int* __restrict__ rs, const int* __restrict__ bsum,
    const int* __restrict__ ecol, const float4* __restrict__ edata,
    float* __restrict__ PQ1)
{
    int idx = blockIdx.x * 256 + threadIdx.x;
    if (idx >= N_NODES * F_INQ) return;
    int node = idx / F_INQ;
    int f = idx - node * F_INQ;
    int end = rs[node] + bsum[node >> 8];
    int start = (node == 0) ? 0 : (rs[node - 1] + bsum[(node - 1) >> 8]);
    float p0 = 0.f, p1 = 0.f, p2 = 0.f, p3 = 0.f, q = 0.f;
    for (int k = start; k < end; ++k) {
        int col = ecol[k];
        float4 ed = edata[k];
        float xv = x[col * F_INQ + f];
        p0 += xv;
        p1 += ed.y * xv;
        p2 += ed.z * xv;
        p3 += ed.w * xv;
        q  += ed.x * xv;
    }
    float* P = PQ1 + node * 52;
    P[f]      = p0;
    P[10 + f] = p1;
    P[20 + f] = p2;
    P[30 + f] = p3;
    P[40 + f] = q;
}

// ---------------------------------------------------------------------------
// K_tf1: thread-per-node transform 1. Node data (52 floats) in VGPRs via
// float4; weights via wave-uniform s_load from Wc1/Wgt1. No LDS, no sync.
// Output packed __half2(g,c), stored as uint4 (4 o's per 16-B store).
// ---------------------------------------------------------------------------
__global__ __launch_bounds__(256, 4) void k_tf1(
    const float* __restrict__ PQ1,
    const float* __restrict__ x,
    const float* __restrict__ Wc1,   // [16][50]
    const float* __restrict__ Wgt1,  // [16][10]
    const float* __restrict__ bias1, const float* __restrict__ bg1,
    __half2* __restrict__ g1c1h)
{
    int node = blockIdx.x * 256 + threadIdx.x;
    if (node >= N_NODES) return;
    float tmp[52];                     // [P0|P1|P2|P3|Q|pad2]
    const float4* Pv = (const float4*)(PQ1 + node * 52);
#pragma unroll
    for (int i = 0; i < 13; ++i) ((float4*)tmp)[i] = Pv[i];
    float xs[10];
    const float2* xv = (const float2*)(x + node * F_INQ);
#pragma unroll
    for (int i = 0; i < 5; ++i) ((float2*)xs)[i] = xv[i];

    uint4* outp = (uint4*)(g1c1h + node * 16);
#pragma unroll
    for (int ob = 0; ob < 4; ++ob) {
        __half2 h[4];
#pragma unroll
        for (int k = 0; k < 4; ++k) {
            int o = ob * 4 + k;
            float ac = bias1[o];
#pragma unroll
            for (int i = 0; i < 40; ++i) ac += tmp[i] * Wc1[o * 50 + i];
#pragma unroll
            for (int j = 0; j < 10; ++j) ac += xs[j] * Wc1[o * 50 + 40 + j];
            float ag = bg1[o];
#pragma unroll
            for (int j = 0; j < 10; ++j) ag += tmp[40 + j] * Wgt1[o * 10 + j];
            h[k] = __floats2half2_rn(ag > 0.f ? ag : 0.f, ac > 0.f ? ac : 0.f);
        }
        uint4 st;
        st.x = *(unsigned int*)&h[0]; st.y = *(unsigned int*)&h[1];
        st.z = *(unsigned int*)&h[2]; st.w = *(unsigned int*)&h[3];
        outp[ob] = st;
    }
}

// ---------------------------------------------------------------------------
// K_edge2: weight-free CSR reduction, layer 2. Lane = (node, f<16).
// One 4-B __half2 load per edge per lane from L2-resident g1c1h. PQ2[n,80].
// ---------------------------------------------------------------------------
__global__ __launch_bounds__(256) void k_edge2(
    const __half2* __restrict__ g1c1h,
    const int* __restrict__ rs, const int* __restrict__ bsum,
    const int* __restrict__ ecol, const float4* __restrict__ edata,
    float* __restrict__ PQ2)
{
    int idx = blockIdx.x * 256 + threadIdx.x;   // 3750 blocks exact
    int node = idx >> 4, f = idx & 15;
    int end = rs[node] + bsum[node >> 8];
    int start = (node == 0) ? 0 : (rs[node - 1] + bsum[(node - 1) >> 8]);
    float p0 = 0.f, p1 = 0.f, p2 = 0.f, p3 = 0.f, q = 0.f;
    for (int k = start; k < end; ++k) {
        int col = ecol[k];
        float4 ed = edata[k];
        float2 gc = __half22float2(g1c1h[col * 16 + f]);
        p0 += gc.y;
        p1 += ed.y * gc.y;
        p2 += ed.z * gc.y;
        p3 += ed.w * gc.y;
        q  += ed.x * gc.x;
    }
    float* P = PQ2 + node * 80;
    P[f]      = p0;
    P[16 + f] = p1;
    P[32 + f] = p2;
    P[48 + f] = p3;
    P[64 + f] = q;
}

// ---------------------------------------------------------------------------
// K_tf2: thread-per-node transform 2 (the R10 fix — was 45 us latency-bound).
// Node data: PQ2 row (80 f32, 20xfloat4) + c1-self (16 half2, 4xuint4) in
// VGPRs; weights via wave-uniform s_load (SGPR operands). 4 independent
// accumulator chains per o-group; float4 stores. No LDS, no sync.
// ---------------------------------------------------------------------------
__global__ __launch_bounds__(256, 4) void k_tf2(
    const float* __restrict__ PQ2,
    const __half2* __restrict__ g1c1h,
    const float* __restrict__ Wc2,   // [32][80]
    const float* __restrict__ Wgt2,  // [32][16]
    const float* __restrict__ bias2, const float* __restrict__ bg2,
    float* __restrict__ g2c2)
{
    int node = blockIdx.x * 256 + threadIdx.x;
    if (node >= N_NODES) return;
    float u[80];                       // [P0|P1|P2|P3 (64) | cs (16)]
    float qv[16];
    const float4* Pv = (const float4*)(PQ2 + node * 80);
#pragma unroll
    for (int i = 0; i < 16; ++i) ((float4*)u)[i] = Pv[i];      // P0..P3
#pragma unroll
    for (int i = 0; i < 4; ++i) ((float4*)qv)[i] = Pv[16 + i]; // Q
    const __half2* cs = g1c1h + node * 16;
#pragma unroll
    for (int f = 0; f < 16; ++f) u[64 + f] = __half22float2(cs[f]).y;

    float4* outp = (float4*)(g2c2 + node * 64);
    // g2 outputs (cols 0..31)
#pragma unroll
    for (int ob = 0; ob < 8; ++ob) {
        float4 a;
        a.x = bg2[ob * 4 + 0]; a.y = bg2[ob * 4 + 1];
        a.z = bg2[ob * 4 + 2]; a.w = bg2[ob * 4 + 3];
#pragma unroll
        for (int j = 0; j < 16; ++j) {
            float v = qv[j];
            a.x += v * Wgt2[(ob * 4 + 0) * 16 + j];
            a.y += v * Wgt2[(ob * 4 + 1) * 16 + j];
            a.z += v * Wgt2[(ob * 4 + 2) * 16 + j];
            a.w += v * Wgt2[(ob * 4 + 3) * 16 + j];
        }
        a.x = a.x > 0.f ? a.x : 0.f; a.y = a.y > 0.f ? a.y : 0.f;
        a.z = a.z > 0.f ? a.z : 0.f; a.w = a.w > 0.f ? a.w : 0.f;
        outp[ob] = a;
    }
    // c2 outputs (cols 32..63)
#pragma unroll
    for (int ob = 0; ob < 8; ++ob) {
        float4 a;
        a.x = bias2[ob * 4 + 0]; a.y = bias2[ob * 4 + 1];
        a.z = bias2[ob * 4 + 2]; a.w = bias2[ob * 4 + 3];
#pragma unroll
        for (int i = 0; i < 80; ++i) {
            float v = u[i];
            a.x += v * Wc2[(ob * 4 + 0) * 80 + i];
            a.y += v * Wc2[(ob * 4 + 1) * 80 + i];
            a.z += v * Wc2[(ob * 4 + 2) * 80 + i];
            a.w += v * Wc2[(ob * 4 + 3) * 80 + i];
        }
        a.x = a.x > 0.f ? a.x : 0.f; a.y = a.y > 0.f ? a.y : 0.f;
        a.z = a.z > 0.f ? a.z : 0.f; a.w = a.w > 0.f ? a.w : 0.f;
        outp[8 + ob] = a;
    }
}

// ---------------------------------------------------------------------------
// K_pool_head: one block per graph, 512 threads; lane = channel j<64;
// LDS-reduce; fused MLP head. No atomics.
// ---------------------------------------------------------------------------
__global__ __launch_bounds__(512) void k_pool_head(
    const float* __restrict__ g2c2,
    const int* __restrict__ gs,
    const float* __restrict__ Wd1, const float* __restrict__ bd1,
    const float* __restrict__ Wd2, const float* __restrict__ bd2,
    const float* __restrict__ Wo,  const float* __restrict__ bo,
    float* __restrict__ out)
{
    __shared__ float red[8][64];
    __shared__ float pl[64];
    __shared__ float h1s[16], h2s[8];
    int g = blockIdx.x;
    int s = gs[g], e = gs[g + 1];
    int wv = threadIdx.x >> 6, j = threadIdx.x & 63;
    float acc = 0.f;
    for (int nn = s + wv; nn < e; nn += 8)
        acc += g2c2[nn * 64 + j];
    red[wv][j] = acc;
    __syncthreads();
    if (wv == 0) {
        float a = red[0][j];
#pragma unroll
        for (int r = 1; r < 8; ++r) a += red[r][j];
        pl[j] = a;
    }
    __syncthreads();
    int t = threadIdx.x;
    if (t < 16) {
        float a = bd1[t];
        for (int k = 0; k < 64; ++k) a += pl[k] * Wd1[k * 16 + t];
        h1s[t] = a > 0.f ? a : 0.f;
    }
    __syncthreads();
    if (t < 8) {
        float a = bd2[t];
        for (int k = 0; k < 16; ++k) a += h1s[k] * Wd2[k * 8 + t];
        h2s[t] = a > 0.f ? a : 0.f;
    }
    __syncthreads();
    if (t == 0) {
        float a = bo[0];
        for (int k = 0; k < 8; ++k) a += h2s[k] * Wo[k];
        out[g] = 1.f / (1.f + expf(-a));
    }
}

// ---------------------------------------------------------------------------
// Workspace layout (all big chunks 64-B aligned):
//   edata E*float4 | PQ1 N*52 f32 | g1c1h N*16 __half2 | PQ2 N*80 f32
//   | g2c2 N*64 f32 | Wblk 4032 f32 | rs[N] | cnt[1] | bsum[256] | gs[G+1]
//   | ecol[E]
// 9 dispatches (memset + prep + scan + fill + edge1 + tf1 + edge2 + tf2 + pool).
// ---------------------------------------------------------------------------
extern "C" void kernel_launch(void* const* d_in, const int* in_sizes, int n_in,
                              void* d_out, int out_size, void* d_ws, size_t ws_size,
                              hipStream_t stream)
{
    const float* x      = (const float*)d_in[0];
    const float* a_vals = (const float*)d_in[1];
    const float* efeat  = (const float*)d_in[2];
    const int*   ei     = (const int*)d_in[3];
    const int*   seg    = (const int*)d_in[4];
    const float* Wg1    = (const float*)d_in[5];
    const float* bg1    = (const float*)d_in[6];
    const float* Wg2    = (const float*)d_in[7];
    const float* bg2    = (const float*)d_in[8];
    const float* We1    = (const float*)d_in[9];
    const float* be1    = (const float*)d_in[10];
    const float* root1  = (const float*)d_in[11];
    const float* bias1  = (const float*)d_in[12];
    const float* We2    = (const float*)d_in[13];
    const float* be2    = (const float*)d_in[14];
    const float* root2  = (const float*)d_in[15];
    const float* bias2  = (const float*)d_in[16];
    const float* Wd1    = (const float*)d_in[17];
    const float* bd1    = (const float*)d_in[18];
    const float* Wd2    = (const float*)d_in[19];
    const float* bd2    = (const float*)d_in[20];
    const float* Wo     = (const float*)d_in[21];
    const float* bo     = (const float*)d_in[22];

    float4*  edata = (float4*)d_ws;
    float*   PQ1   = (float*)(edata + N_EDGES);
    __half2* g1c1h = (__half2*)(PQ1 + (size_t)N_NODES * 52);
    float*   PQ2   = (float*)(g1c1h + (size_t)N_NODES * 16);
    float*   g2c2  = PQ2 + (size_t)N_NODES * 80;
    float*   Wblk  = g2c2 + (size_t)N_NODES * 64;
    float*   Wc1   = Wblk;          // [16][50] = 800
    float*   Wgt1  = Wblk + 800;    // [16][10] = 160
    float*   Wc2   = Wblk + 960;    // [32][80] = 2560
    float*   Wgt2  = Wblk + 3520;   // [32][16] = 512
    int*     rs    = (int*)(Wblk + 4032);
    int*     cnt   = rs + N_NODES;
    int*     bsum  = cnt + 1;
    int*     gs    = bsum + 256;
    int*     ecol  = gs + (G_DIM + 1);
    float*   out   = (float*)d_out;

    hipMemsetAsync(rs, 0, sizeof(int) * (N_NODES + 1), stream);  // rs + cnt

    // CSR build + graph segments + weight transpose (3 dispatches)
    k_prep<<<NB_EDGE + NB_SCAN + 1, 256, 0, stream>>>(
        ei, rs, seg, gs, Wg1, We1, be1, root1, Wg2, We2, be2, root2, Wblk);
    k_scan<<<NB_SCAN, 256, 0, stream>>>(rs, bsum, cnt);
    k_fill<<<NB_EDGE, 256, 0, stream>>>(ei, a_vals, efeat, rs, bsum, ecol, edata);

    // Layer 1
    k_edge1<<<(N_NODES * F_INQ + 255) / 256, 256, 0, stream>>>(
        x, rs, bsum, ecol, edata, PQ1);
    k_tf1<<<(N_NODES + 255) / 256, 256, 0, stream>>>(
        PQ1, x, Wc1, Wgt1, bias1, bg1, g1c1h);

    // Layer 2
    k_edge2<<<N_NODES * 16 / 256, 256, 0, stream>>>(g1c1h, rs, bsum, ecol, edata, PQ2);
    k_tf2<<<(N_NODES + 255) / 256, 256, 0, stream>>>(
        PQ2, g1c1h, Wc2, Wgt2, bias2, bg2, g2c2);

    // Pool + MLP head
    k_pool_head<<<G_DIM, 512, 0, stream>>>(g2c2, gs, Wd1, bd1, Wd2, bd2, Wo, bo, out);
}